// Round 9
// baseline (218.220 us; speedup 1.0000x reference)
//
#include <hip/hip_runtime.h>
#include <math.h>

#define BB 8
#define CC 128
#define HH 128
#define WW 128
#define HWs (HH * WW)

#define TH 8
#define TW 8
#define NP 64            // pixels per block (8x8)
#define NCX 10
#define NCOL 100

#define K7 7
#define K19 19
#define K43 43

#define XPAD 24          // front zero-pad (channels); slots [0,24) & [152,184) are zero
#define CSX 184          // column stride in ushorts = 368 B = 23 x 16B
#define CSV 168          // (fallback kernel) vol stride
#define VSUB 40          // (fallback kernel) vol subchunk stride

struct Kers { float k7[K7]; float k19[K19]; float k43[K43]; };

__device__ __forceinline__ ushort f2bf(float f) {        // RNE f32 -> bf16
    uint u = __float_as_uint(f);
    u += 0x7FFFu + ((u >> 16) & 1u);
    return (ushort)(u >> 16);
}
__device__ __forceinline__ float bflo(uint u) { return __uint_as_float(u << 16); }
__device__ __forceinline__ float bfhi(uint u) { return __uint_as_float(u & 0xFFFF0000u); }

// stage one 8x8 tile (64 cols x 184 padded slots) of x into LDS as bf16.
// No spatial halo: tiles exactly cover the image -> no border predicate.
__device__ __forceinline__ void stage_tile(const float* __restrict__ xb,
                                           ushort* __restrict__ xs,
                                           int tid, int h0, int w0) {
    for (int idx = tid; idx < NP * 46; idx += 256) {
        const int q  = idx & 63;          // pixel in tile (lane-fastest -> coalesced)
        const int s4 = idx >> 6;          // 4-ushort slot 0..45
        uint lo = 0, hi = 0;
        if (s4 >= 6 && s4 < 38) {
            const int c  = 4 * s4 - XPAD;
            const int hh = h0 + (q >> 3), ww = w0 + (q & 7);
            const float* gp = xb + (size_t)c * HWs + hh * WW + ww;
            lo = (uint)f2bf(gp[0])       | ((uint)f2bf(gp[HWs])     << 16);
            hi = (uint)f2bf(gp[2 * HWs]) | ((uint)f2bf(gp[3 * HWs]) << 16);
        }
        *(uint2*)(xs + q * CSX + 4 * s4) = make_uint2(lo, hi);
    }
}

// ================= K1: vol = |conv19|, band-mean, MLP ========================
__global__ void __launch_bounds__(256, 4) vol_kernel(
        const float* __restrict__ x, const float* __restrict__ meta,
        const float* __restrict__ w1, const float* __restrict__ b1,
        const float* __restrict__ w2, const float* __restrict__ b2,
        ushort* __restrict__ volg, float* __restrict__ mimgg,
        float* __restrict__ abgg, Kers kers) {
    __shared__ __align__(16) ushort xs[NP * CSX];   // 23.5 KB
    __shared__ float hbuf[192];

    const int tid = threadIdx.x;
    const int wg  = blockIdx.x;
    const int swz = (wg & 7) * 256 + (wg >> 3);     // XCD k owns batch k
    const int b   = swz >> 8;
    const int rem = swz & 255;
    const int h0  = (rem >> 4) * TH, w0 = (rem & 15) * TW;

    if (wg == 0 && tid < 192) {                     // MLP stage 1, all 8 batches
        const int bb = tid / 24, j = tid - bb * 24;
        float s = b1[j];
        #pragma unroll
        for (int i = 0; i < 12; ++i) s = fmaf(meta[bb * 12 + i], w1[j * 12 + i], s);
        hbuf[tid] = fmaxf(s, 0.0f);
    }
    stage_tile(x + (size_t)b * CC * HWs, xs, tid, h0, w0);
    __syncthreads();
    if (wg == 0 && tid < 24) {                      // MLP stage 2 -> abg to ws
        const int bb = tid / 3, o = tid - bb * 3;
        float s = b2[o];
        #pragma unroll
        for (int j = 0; j < 24; ++j) s = fmaf(hbuf[bb * 24 + j], w2[o * 24 + j], s);
        abgg[tid] = 1.0f / (1.0f + expf(-s));
    }

    // conv19: one (pixel q, 32-ch chunk k) per thread; tap-outer accumulators
    const int q = tid & 63, k = tid >> 6;
    const int hh = h0 + (q >> 3), ww = w0 + (q & 7);
    const size_t pixg = ((size_t)b * HH + hh) * WW + ww;
    {
        float acc[32];
        #pragma unroll
        for (int m = 0; m < 32; ++m) acc[m] = 0.0f;
        const uint4* wp = (const uint4*)(xs + q * CSX + 32 * k + 8); // slot 32k+8, 16B aligned
        #pragma unroll
        for (int t = 0; t < 8; ++t) {
            const uint4 u = wp[t];
            float w8[8];
            w8[0]=bflo(u.x); w8[1]=bfhi(u.x); w8[2]=bflo(u.y); w8[3]=bfhi(u.y);
            w8[4]=bflo(u.z); w8[5]=bfhi(u.z); w8[6]=bflo(u.w); w8[7]=bfhi(u.w);
            #pragma unroll
            for (int e = 0; e < 8; ++e) {
                const int i = 8 * t + e;             // window index; out m needs j=i-m-7 in [0,19)
                #pragma unroll
                for (int m = 0; m < 32; ++m) {
                    const int j = i - m - 7;
                    if (j >= 0 && j < K19) acc[m] = fmaf(kers.k19[j], w8[e], acc[m]);
                }
            }
        }
        uint ov[16];
        #pragma unroll
        for (int m = 0; m < 32; ++m) {
            const ushort hv = f2bf(fabsf(acc[m]));
            if ((m & 1) == 0) ov[m >> 1] = hv; else ov[m >> 1] |= (uint)hv << 16;
        }
        uint4* vp = (uint4*)(volg + pixg * CC + 32 * k);
        vp[0] = make_uint4(ov[0],  ov[1],  ov[2],  ov[3]);
        vp[1] = make_uint4(ov[4],  ov[5],  ov[6],  ov[7]);
        vp[2] = make_uint4(ov[8],  ov[9],  ov[10], ov[11]);
        vp[3] = make_uint4(ov[12], ov[13], ov[14], ov[15]);
    }
    if (tid < NP) {                                 // band-mean per pixel column
        const uint4* cp = (const uint4*)(xs + tid * CSX + XPAD);
        float s = 0.0f;
        #pragma unroll
        for (int t = 0; t < 16; ++t) {
            const uint4 u = cp[t];
            s += bflo(u.x) + bfhi(u.x) + bflo(u.y) + bfhi(u.y)
               + bflo(u.z) + bfhi(u.z) + bflo(u.w) + bfhi(u.w);
        }
        const int hh2 = h0 + (tid >> 3), ww2 = w0 + (tid & 7);
        mimgg[((size_t)b * HH + hh2) * WW + ww2] = s * (1.0f / CC);
    }
}

// ================= K2: conv7/conv43 + vol stencil + combine ==================
__global__ void __launch_bounds__(256, 4) grad_kernel(
        const float* __restrict__ x, const ushort* __restrict__ volg,
        const float* __restrict__ mimgg, const float* __restrict__ abgg,
        float* __restrict__ out, Kers kers) {
    __shared__ __align__(16) ushort xs[NP * CSX];   // 23.5 KB, only LDS use

    const int tid = threadIdx.x;
    const int wg  = blockIdx.x;
    const int swz = (wg & 7) * 256 + (wg >> 3);
    const int b   = swz >> 8;
    const int rem = swz & 255;
    const int h0  = (rem >> 4) * TH, w0 = (rem & 15) * TW;

    stage_tile(x + (size_t)b * CC * HWs, xs, tid, h0, w0);
    __syncthreads();

    const int p = tid >> 2, sub = tid & 3;          // 4 lanes share a pixel
    const int py = p >> 3, px = p & 7;
    const int h = h0 + py, w = w0 + px;
    const size_t pixg = ((size_t)b * HH + h) * WW + w;

    // A) conv7 + conv43, tap-outer accumulators (64 accs, 8-float rolling input)
    float a43[32], a7[32];
    #pragma unroll
    for (int m = 0; m < 32; ++m) { a43[m] = 0.0f; a7[m] = 0.0f; }
    {
        const uint4* ap = (const uint4*)(xs + p * CSX + 32 * sub);
        #pragma unroll
        for (int t = 0; t < 10; ++t) {
            const uint4 u = ap[t];
            float w8[8];
            w8[0]=bflo(u.x); w8[1]=bfhi(u.x); w8[2]=bflo(u.y); w8[3]=bfhi(u.y);
            w8[4]=bflo(u.z); w8[5]=bfhi(u.z); w8[6]=bflo(u.w); w8[7]=bfhi(u.w);
            #pragma unroll
            for (int e = 0; e < 8; ++e) {
                const int i = 8 * t + e;            // out m: conv43 j=i-m-3; conv7 j=i-m-21
                #pragma unroll
                for (int m = 0; m < 32; ++m) {
                    const int j43 = i - m - 3;
                    if (j43 >= 0 && j43 < K43) a43[m] = fmaf(kers.k43[j43], w8[e], a43[m]);
                    const int j7 = i - m - 21;
                    if (j7 >= 0 && j7 < K7)    a7[m]  = fmaf(kers.k7[j7],  w8[e], a7[m]);
                }
            }
        }
    }
    float g1 = 0.0f, g3 = 0.0f;
    #pragma unroll
    for (int m = 0; m < 32; ++m) { g1 += fabsf(a7[m]); g3 += fabsf(a43[m]); }

    // B) vol 9-point stencil straight from global (L2/L3; same-XCD producer)
    bool vld[9];
    const ushort* vb[9];
    #pragma unroll
    for (int n = 0; n < 9; ++n) {
        const int dy = n / 3 - 1, dx = n % 3 - 1;
        const int hn = h + dy, wn = w + dx;
        vld[n] = ((unsigned)hn < HH) && ((unsigned)wn < WW);
        const size_t pn = vld[n] ? (pixg + dy * WW + dx) : pixg;
        vb[n] = volg + pn * CC + 32 * sub;
    }
    float g2 = 0.0f, macc = 0.0f;
    #pragma unroll
    for (int ss = 0; ss < 4; ++ss) {
        uint4 u[9];
        #pragma unroll
        for (int n = 0; n < 9; ++n)
            u[n] = vld[n] ? *(const uint4*)(vb[n] + 8 * ss) : make_uint4(0, 0, 0, 0);
        #pragma unroll
        for (int t = 0; t < 8; ++t) {
            float v[9];
            #pragma unroll
            for (int n = 0; n < 9; ++n) {
                const uint wsel = (t & 4) ? ((t & 2) ? u[n].w : u[n].z)
                                          : ((t & 2) ? u[n].y : u[n].x);
                v[n] = (t & 1) ? bfhi(wsel) : bflo(wsel);
            }
            g2 += v[4];
            const float mx = (v[2] - v[0]) + 2.0f * (v[5] - v[3]) + (v[8] - v[6]);
            const float my = (v[6] - v[0]) + 2.0f * (v[7] - v[1]) + (v[8] - v[2]);
            macc += sqrtf(mx * mx + my * my + 1e-8f);
        }
    }
    g1   += __shfl_xor(g1, 1);   g1   += __shfl_xor(g1, 2);
    g2   += __shfl_xor(g2, 1);   g2   += __shfl_xor(g2, 2);
    g3   += __shfl_xor(g3, 1);   g3   += __shfl_xor(g3, 2);
    macc += __shfl_xor(macc, 1); macc += __shfl_xor(macc, 2);

    if (sub == 0) {
        const float spec = fmaxf(fmaxf(g1, g2), g3) * (1.0f / CC);
        const float mix  = macc * (1.0f / CC);
        float mg[9];
        #pragma unroll
        for (int n = 0; n < 9; ++n) {
            const int dy = n / 3 - 1, dx = n % 3 - 1;
            mg[n] = vld[n] ? mimgg[pixg + dy * WW + dx] : 0.0f;
        }
        const float gx = (mg[2] - mg[0]) + 2.0f * (mg[5] - mg[3]) + (mg[8] - mg[6]);
        const float gy = (mg[6] - mg[0]) + 2.0f * (mg[7] - mg[1]) + (mg[8] - mg[2]);
        const float sg2 = gx * gx + gy * gy + 1e-8f;  // spatial_grad^2 (sqrt folded)
        const float al = abgg[b * 3 + 0], be = abgg[b * 3 + 1], ga = abgg[b * 3 + 2];
        out[pixg] = sqrtf(al * sg2 + be * spec * spec + ga * mix * mix + 1e-8f);
    }
}

// ============ fallback: round-8 fused kernel (used if ws too small) ==========
__global__ void __launch_bounds__(256, 2) holo_kernel(
        const float* __restrict__ x, const float* __restrict__ meta,
        const float* __restrict__ w1, const float* __restrict__ b1,
        const float* __restrict__ w2, const float* __restrict__ b2,
        float* __restrict__ out, Kers kers) {
    __shared__ __align__(16) ushort xs[NCOL * CSX];
    __shared__ __align__(16) ushort vol[NCOL * CSV];
    __shared__ float mimg[NCOL];
    __shared__ float hbuf[24];
    __shared__ float abg[3];

    const int tid = threadIdx.x;
    const int wg  = blockIdx.x;
    const int swz = (wg & 7) * 256 + (wg >> 3);
    const int b   = swz >> 8;
    const int rem = swz & 255;
    const int h0  = (rem >> 4) * TH;
    const int w0  = (rem & 15) * TW;

    if (tid < 24) {
        float s = b1[tid];
        #pragma unroll
        for (int i = 0; i < 12; ++i) s = fmaf(meta[b * 12 + i], w1[tid * 12 + i], s);
        hbuf[tid] = fmaxf(s, 0.0f);
    }
    const float* xb = x + (size_t)b * (CC * HWs);
    for (int idx = tid; idx < NCOL * 46; idx += 256) {
        const int q  = idx % NCOL;
        const int s4 = idx / NCOL;
        uint lo = 0, hi = 0;
        if (s4 >= 6 && s4 < 38) {
            const int c  = 4 * s4 - XPAD;
            const int hh = h0 - 1 + q / NCX, ww = w0 - 1 + q % NCX;
            if ((unsigned)hh < HH && (unsigned)ww < WW) {
                const float* gp = xb + (size_t)c * HWs + hh * WW + ww;
                lo = (uint)f2bf(gp[0])       | ((uint)f2bf(gp[HWs])     << 16);
                hi = (uint)f2bf(gp[2 * HWs]) | ((uint)f2bf(gp[3 * HWs]) << 16);
            }
        }
        *(uint2*)(xs + q * CSX + 4 * s4) = make_uint2(lo, hi);
    }
    __syncthreads();
    if (tid < 3) {
        float s = b2[tid];
        #pragma unroll
        for (int j = 0; j < 24; ++j) s = fmaf(hbuf[j], w2[tid * 24 + j], s);
        abg[tid] = 1.0f / (1.0f + expf(-s));
    }
    for (int it = tid; it < NCOL * 4; it += 256) {
        const int q = it % NCOL, k = it / NCOL;
        const uint4* wp = (const uint4*)(xs + q * CSX + 8 + 32 * k);
        float f2[64];
        #pragma unroll
        for (int t = 0; t < 8; ++t) {
            uint4 u = wp[t];
            f2[8*t+0]=bflo(u.x); f2[8*t+1]=bfhi(u.x); f2[8*t+2]=bflo(u.y); f2[8*t+3]=bfhi(u.y);
            f2[8*t+4]=bflo(u.z); f2[8*t+5]=bfhi(u.z); f2[8*t+6]=bflo(u.w); f2[8*t+7]=bfhi(u.w);
        }
        uint ov[16];
        #pragma unroll
        for (int m = 0; m < 32; ++m) {
            float s = 0.0f;
            #pragma unroll
            for (int j = 0; j < K19; ++j) s = fmaf(kers.k19[j], f2[m + 7 + j], s);
            const ushort hv = f2bf(fabsf(s));
            if ((m & 1) == 0) ov[m >> 1] = hv; else ov[m >> 1] |= (uint)hv << 16;
        }
        uint4* vp = (uint4*)(vol + q * CSV + VSUB * k);
        vp[0] = make_uint4(ov[0],  ov[1],  ov[2],  ov[3]);
        vp[1] = make_uint4(ov[4],  ov[5],  ov[6],  ov[7]);
        vp[2] = make_uint4(ov[8],  ov[9],  ov[10], ov[11]);
        vp[3] = make_uint4(ov[12], ov[13], ov[14], ov[15]);
    }
    if (tid >= 156) {
        const int col = tid - 156;
        const uint4* cp = (const uint4*)(xs + col * CSX + XPAD);
        float s = 0.0f;
        #pragma unroll
        for (int t = 0; t < 16; ++t) {
            uint4 u = cp[t];
            s += bflo(u.x) + bfhi(u.x) + bflo(u.y) + bfhi(u.y)
               + bflo(u.z) + bfhi(u.z) + bflo(u.w) + bfhi(u.w);
        }
        mimg[col] = s * (1.0f / CC);
    }
    __syncthreads();

    const int p = tid >> 2, sub = tid & 3;
    const int py = p >> 3, px = p & 7;
    const int q  = (py + 1) * NCX + (px + 1);
    float g1 = 0.0f, g3 = 0.0f;
    {
        float f[80];
        const uint4* ap = (const uint4*)(xs + q * CSX + 32 * sub);
        #pragma unroll
        for (int t = 0; t < 10; ++t) {
            uint4 u = ap[t];
            f[8*t+0]=bflo(u.x); f[8*t+1]=bfhi(u.x); f[8*t+2]=bflo(u.y); f[8*t+3]=bfhi(u.y);
            f[8*t+4]=bflo(u.z); f[8*t+5]=bfhi(u.z); f[8*t+6]=bflo(u.w); f[8*t+7]=bfhi(u.w);
        }
        #pragma unroll
        for (int m = 0; m < 32; ++m) {
            float s43 = 0.0f;
            #pragma unroll
            for (int j = 0; j < K43; ++j) s43 = fmaf(kers.k43[j], f[m + 3 + j], s43);
            float s7 = 0.0f;
            #pragma unroll
            for (int j = 0; j < K7; ++j) s7 = fmaf(kers.k7[j], f[m + 21 + j], s7);
            g3 += fabsf(s43);
            g1 += fabsf(s7);
        }
    }
    float g2 = 0.0f, macc = 0.0f;
    const int nq[9] = { q-11, q-10, q-9, q-1, q, q+1, q+9, q+10, q+11 };
    #pragma unroll
    for (int ss = 0; ss < 4; ++ss) {
        uint4 u[9];
        #pragma unroll
        for (int n = 0; n < 9; ++n)
            u[n] = *(const uint4*)(vol + nq[n] * CSV + sub * VSUB + 8 * ss);
        #pragma unroll
        for (int t = 0; t < 8; ++t) {
            float v[9];
            #pragma unroll
            for (int n = 0; n < 9; ++n) {
                const uint wsel = (t & 4) ? ((t & 2) ? u[n].w : u[n].z)
                                          : ((t & 2) ? u[n].y : u[n].x);
                v[n] = (t & 1) ? bfhi(wsel) : bflo(wsel);
            }
            g2 += v[4];
            const float mx = (v[2] - v[0]) + 2.0f * (v[5] - v[3]) + (v[8] - v[6]);
            const float my = (v[6] - v[0]) + 2.0f * (v[7] - v[1]) + (v[8] - v[2]);
            macc += sqrtf(mx * mx + my * my + 1e-8f);
        }
    }
    g1   += __shfl_xor(g1, 1);   g1   += __shfl_xor(g1, 2);
    g2   += __shfl_xor(g2, 1);   g2   += __shfl_xor(g2, 2);
    g3   += __shfl_xor(g3, 1);   g3   += __shfl_xor(g3, 2);
    macc += __shfl_xor(macc, 1); macc += __shfl_xor(macc, 2);
    if (sub == 0) {
        const float spec = fmaxf(fmaxf(g1, g2), g3) * (1.0f / CC);
        const float mix  = macc * (1.0f / CC);
        const float m_mm = mimg[q-11], m_m0 = mimg[q-10], m_mp = mimg[q-9];
        const float m_0m = mimg[q-1],                      m_0p = mimg[q+1];
        const float m_pm = mimg[q+9],  m_p0 = mimg[q+10],  m_pp = mimg[q+11];
        const float gx = (m_mp - m_mm) + 2.0f * (m_0p - m_0m) + (m_pp - m_pm);
        const float gy = (m_pm - m_mm) + 2.0f * (m_p0 - m_m0) + (m_pp - m_mp);
        const float sg2 = gx * gx + gy * gy + 1e-8f;
        const float al = abg[0], be = abg[1], ga = abg[2];
        const float o = sqrtf(al * sg2 + be * spec * spec + ga * mix * mix + 1e-8f);
        out[((size_t)b * HH + (h0 + py)) * WW + (w0 + px)] = o;
    }
}

// ---------------- host side --------------------------------------------------
static void make_ker(float sigma, int k, float* outk) {
    int half = k / 2;
    float asum = 0.0f;
    for (int i = 0; i < k; ++i) {
        float xx = (float)(i - half);
        float v = -xx / (sigma * sigma * sigma) * expf(-xx * xx / (2.0f * sigma * sigma));
        outk[i] = v;
        asum += fabsf(v);
    }
    for (int i = 0; i < k; ++i) outk[i] /= asum;
}

extern "C" void kernel_launch(void* const* d_in, const int* in_sizes, int n_in,
                              void* d_out, int out_size, void* d_ws, size_t ws_size,
                              hipStream_t stream) {
    const float* x    = (const float*)d_in[0];
    const float* meta = (const float*)d_in[1];
    const float* w1   = (const float*)d_in[2];
    const float* b1   = (const float*)d_in[3];
    const float* w2   = (const float*)d_in[4];
    const float* b2   = (const float*)d_in[5];
    float* outp = (float*)d_out;

    Kers kers;
    make_ker(1.0f, K7,  kers.k7);
    make_ker(3.0f, K19, kers.k19);
    make_ker(7.0f, K43, kers.k43);

    const size_t VOLB  = (size_t)BB * HH * WW * CC * sizeof(ushort); // 33,554,432
    const size_t MIMGB = (size_t)BB * HH * WW * sizeof(float);       //    524,288
    const size_t ABGB  = 24 * sizeof(float);

    if (ws_size >= VOLB + MIMGB + ABGB) {
        ushort* volg  = (ushort*)d_ws;
        float*  mimgg = (float*)((char*)d_ws + VOLB);
        float*  abgg  = (float*)((char*)d_ws + VOLB + MIMGB);
        vol_kernel<<<BB * 16 * 16, 256, 0, stream>>>(x, meta, w1, b1, w2, b2,
                                                     volg, mimgg, abgg, kers);
        grad_kernel<<<BB * 16 * 16, 256, 0, stream>>>(x, volg, mimgg, abgg,
                                                      outp, kers);
    } else {
        holo_kernel<<<BB * 16 * 16, 256, 0, stream>>>(x, meta, w1, b1, w2, b2,
                                                      outp, kers);
    }
}

// Round 10
// 202.949 us; speedup vs baseline: 1.0752x; 1.0752x over previous
//
#include <hip/hip_runtime.h>
#include <math.h>

#define BB 8
#define CC 128
#define HH 128
#define WW 128
#define HWs (HH * WW)

#define TH 8
#define TW 8
#define NP 64            // pixels per block (8x8)
#define NCX 10
#define NCOL 100

#define K7 7
#define K19 19
#define K43 43

#define XPAD 24          // front zero-pad (channels); slots [0,24) & [152,184) are zero
#define CSX 184          // column stride in ushorts = 368 B = 23 x 16B
#define CSV 168          // (fallback kernel) vol stride
#define VSUB 40          // (fallback kernel) vol subchunk stride

struct Kers { float k7[K7]; float k19[K19]; float k43[K43]; };

__device__ __forceinline__ ushort f2bf(float f) {        // RNE f32 -> bf16
    uint u = __float_as_uint(f);
    u += 0x7FFFu + ((u >> 16) & 1u);
    return (ushort)(u >> 16);
}
__device__ __forceinline__ float bflo(uint u) { return __uint_as_float(u << 16); }
__device__ __forceinline__ float bfhi(uint u) { return __uint_as_float(u & 0xFFFF0000u); }

// stage one 8x8 tile (64 cols x 184 padded slots) of x into LDS as bf16.
// No spatial halo: tiles exactly cover the image -> no border predicate.
__device__ __forceinline__ void stage_tile(const float* __restrict__ xb,
                                           ushort* __restrict__ xs,
                                           int tid, int h0, int w0) {
    for (int idx = tid; idx < NP * 46; idx += 256) {
        const int q  = idx & 63;          // pixel in tile (lane-fastest -> coalesced)
        const int s4 = idx >> 6;          // 4-ushort slot 0..45
        uint lo = 0, hi = 0;
        if (s4 >= 6 && s4 < 38) {
            const int c  = 4 * s4 - XPAD;
            const int hh = h0 + (q >> 3), ww = w0 + (q & 7);
            const float* gp = xb + (size_t)c * HWs + hh * WW + ww;
            lo = (uint)f2bf(gp[0])       | ((uint)f2bf(gp[HWs])     << 16);
            hi = (uint)f2bf(gp[2 * HWs]) | ((uint)f2bf(gp[3 * HWs]) << 16);
        }
        *(uint2*)(xs + q * CSX + 4 * s4) = make_uint2(lo, hi);
    }
}

// ================= K1: vol = |conv19|, band-mean, MLP ========================
// launch_bounds(256,2): VGPR cap 256 -> acc[32]+w8[8] stay in registers.
// (256,4) in the previous round capped VGPR at 64 and spilled to scratch.
__global__ void __launch_bounds__(256, 2) vol_kernel(
        const float* __restrict__ x, const float* __restrict__ meta,
        const float* __restrict__ w1, const float* __restrict__ b1,
        const float* __restrict__ w2, const float* __restrict__ b2,
        ushort* __restrict__ volg, float* __restrict__ mimgg,
        float* __restrict__ abgg, Kers kers) {
    __shared__ __align__(16) ushort xs[NP * CSX];   // 23.5 KB
    __shared__ float hbuf[192];

    const int tid = threadIdx.x;
    const int wg  = blockIdx.x;
    const int swz = (wg & 7) * 256 + (wg >> 3);     // XCD k owns batch k
    const int b   = swz >> 8;
    const int rem = swz & 255;
    const int h0  = (rem >> 4) * TH, w0 = (rem & 15) * TW;

    if (wg == 0 && tid < 192) {                     // MLP stage 1, all 8 batches
        const int bb = tid / 24, j = tid - bb * 24;
        float s = b1[j];
        #pragma unroll
        for (int i = 0; i < 12; ++i) s = fmaf(meta[bb * 12 + i], w1[j * 12 + i], s);
        hbuf[tid] = fmaxf(s, 0.0f);
    }
    stage_tile(x + (size_t)b * CC * HWs, xs, tid, h0, w0);
    __syncthreads();
    if (wg == 0 && tid < 24) {                      // MLP stage 2 -> abg to ws
        const int bb = tid / 3, o = tid - bb * 3;
        float s = b2[o];
        #pragma unroll
        for (int j = 0; j < 24; ++j) s = fmaf(hbuf[bb * 24 + j], w2[o * 24 + j], s);
        abgg[tid] = 1.0f / (1.0f + expf(-s));
    }

    // conv19: one (pixel q, 32-ch chunk k) per thread; tap-outer accumulators
    const int q = tid & 63, k = tid >> 6;
    const int hh = h0 + (q >> 3), ww = w0 + (q & 7);
    const size_t pixg = ((size_t)b * HH + hh) * WW + ww;
    {
        float acc[32];
        #pragma unroll
        for (int m = 0; m < 32; ++m) acc[m] = 0.0f;
        const uint4* wp = (const uint4*)(xs + q * CSX + 32 * k + 8); // slot 32k+8, 16B aligned
        #pragma unroll
        for (int t = 0; t < 8; ++t) {
            const uint4 u = wp[t];
            float w8[8];
            w8[0]=bflo(u.x); w8[1]=bfhi(u.x); w8[2]=bflo(u.y); w8[3]=bfhi(u.y);
            w8[4]=bflo(u.z); w8[5]=bfhi(u.z); w8[6]=bflo(u.w); w8[7]=bfhi(u.w);
            #pragma unroll
            for (int e = 0; e < 8; ++e) {
                const int i = 8 * t + e;             // window index; out m needs j=i-m-7 in [0,19)
                #pragma unroll
                for (int m = 0; m < 32; ++m) {
                    const int j = i - m - 7;
                    if (j >= 0 && j < K19) acc[m] = fmaf(kers.k19[j], w8[e], acc[m]);
                }
            }
        }
        uint ov[16];
        #pragma unroll
        for (int m = 0; m < 32; ++m) {
            const ushort hv = f2bf(fabsf(acc[m]));
            if ((m & 1) == 0) ov[m >> 1] = hv; else ov[m >> 1] |= (uint)hv << 16;
        }
        uint4* vp = (uint4*)(volg + pixg * CC + 32 * k);
        vp[0] = make_uint4(ov[0],  ov[1],  ov[2],  ov[3]);
        vp[1] = make_uint4(ov[4],  ov[5],  ov[6],  ov[7]);
        vp[2] = make_uint4(ov[8],  ov[9],  ov[10], ov[11]);
        vp[3] = make_uint4(ov[12], ov[13], ov[14], ov[15]);
    }
    if (tid < NP) {                                 // band-mean per pixel column
        const uint4* cp = (const uint4*)(xs + tid * CSX + XPAD);
        float s = 0.0f;
        #pragma unroll
        for (int t = 0; t < 16; ++t) {
            const uint4 u = cp[t];
            s += bflo(u.x) + bfhi(u.x) + bflo(u.y) + bfhi(u.y)
               + bflo(u.z) + bfhi(u.z) + bflo(u.w) + bfhi(u.w);
        }
        const int hh2 = h0 + (tid >> 3), ww2 = w0 + (tid & 7);
        mimgg[((size_t)b * HH + hh2) * WW + ww2] = s * (1.0f / CC);
    }
}

// ================= K2: conv7/conv43 + vol stencil + combine ==================
// launch_bounds(256,2): the a43[32]+a7[32] accumulator set needs ~100+ VGPRs;
// (256,4) forced 64 VGPRs -> 175 MB scratch spill (round-9 counters).
__global__ void __launch_bounds__(256, 2) grad_kernel(
        const float* __restrict__ x, const ushort* __restrict__ volg,
        const float* __restrict__ mimgg, const float* __restrict__ abgg,
        float* __restrict__ out, Kers kers) {
    __shared__ __align__(16) ushort xs[NP * CSX];   // 23.5 KB, only LDS use

    const int tid = threadIdx.x;
    const int wg  = blockIdx.x;
    const int swz = (wg & 7) * 256 + (wg >> 3);
    const int b   = swz >> 8;
    const int rem = swz & 255;
    const int h0  = (rem >> 4) * TH, w0 = (rem & 15) * TW;

    stage_tile(x + (size_t)b * CC * HWs, xs, tid, h0, w0);
    __syncthreads();

    const int p = tid >> 2, sub = tid & 3;          // 4 lanes share a pixel
    const int py = p >> 3, px = p & 7;
    const int h = h0 + py, w = w0 + px;
    const size_t pixg = ((size_t)b * HH + h) * WW + w;

    // A) conv7 + conv43, tap-outer accumulators (64 accs, 8-float rolling input)
    float a43[32], a7[32];
    #pragma unroll
    for (int m = 0; m < 32; ++m) { a43[m] = 0.0f; a7[m] = 0.0f; }
    {
        const uint4* ap = (const uint4*)(xs + p * CSX + 32 * sub);
        #pragma unroll
        for (int t = 0; t < 10; ++t) {
            const uint4 u = ap[t];
            float w8[8];
            w8[0]=bflo(u.x); w8[1]=bfhi(u.x); w8[2]=bflo(u.y); w8[3]=bfhi(u.y);
            w8[4]=bflo(u.z); w8[5]=bfhi(u.z); w8[6]=bflo(u.w); w8[7]=bfhi(u.w);
            #pragma unroll
            for (int e = 0; e < 8; ++e) {
                const int i = 8 * t + e;            // out m: conv43 j=i-m-3; conv7 j=i-m-21
                #pragma unroll
                for (int m = 0; m < 32; ++m) {
                    const int j43 = i - m - 3;
                    if (j43 >= 0 && j43 < K43) a43[m] = fmaf(kers.k43[j43], w8[e], a43[m]);
                    const int j7 = i - m - 21;
                    if (j7 >= 0 && j7 < K7)    a7[m]  = fmaf(kers.k7[j7],  w8[e], a7[m]);
                }
            }
        }
    }
    float g1 = 0.0f, g3 = 0.0f;
    #pragma unroll
    for (int m = 0; m < 32; ++m) { g1 += fabsf(a7[m]); g3 += fabsf(a43[m]); }

    // B) vol 9-point stencil straight from global (L2/L3; same-XCD producer)
    bool vld[9];
    const ushort* vb[9];
    #pragma unroll
    for (int n = 0; n < 9; ++n) {
        const int dy = n / 3 - 1, dx = n % 3 - 1;
        const int hn = h + dy, wn = w + dx;
        vld[n] = ((unsigned)hn < HH) && ((unsigned)wn < WW);
        const size_t pn = vld[n] ? (pixg + dy * WW + dx) : pixg;
        vb[n] = volg + pn * CC + 32 * sub;
    }
    float g2 = 0.0f, macc = 0.0f;
    #pragma unroll
    for (int ss = 0; ss < 4; ++ss) {
        uint4 u[9];
        #pragma unroll
        for (int n = 0; n < 9; ++n)
            u[n] = vld[n] ? *(const uint4*)(vb[n] + 8 * ss) : make_uint4(0, 0, 0, 0);
        #pragma unroll
        for (int t = 0; t < 8; ++t) {
            float v[9];
            #pragma unroll
            for (int n = 0; n < 9; ++n) {
                const uint wsel = (t & 4) ? ((t & 2) ? u[n].w : u[n].z)
                                          : ((t & 2) ? u[n].y : u[n].x);
                v[n] = (t & 1) ? bfhi(wsel) : bflo(wsel);
            }
            g2 += v[4];
            const float mx = (v[2] - v[0]) + 2.0f * (v[5] - v[3]) + (v[8] - v[6]);
            const float my = (v[6] - v[0]) + 2.0f * (v[7] - v[1]) + (v[8] - v[2]);
            macc += sqrtf(mx * mx + my * my + 1e-8f);
        }
    }
    g1   += __shfl_xor(g1, 1);   g1   += __shfl_xor(g1, 2);
    g2   += __shfl_xor(g2, 1);   g2   += __shfl_xor(g2, 2);
    g3   += __shfl_xor(g3, 1);   g3   += __shfl_xor(g3, 2);
    macc += __shfl_xor(macc, 1); macc += __shfl_xor(macc, 2);

    if (sub == 0) {
        const float spec = fmaxf(fmaxf(g1, g2), g3) * (1.0f / CC);
        const float mix  = macc * (1.0f / CC);
        float mg[9];
        #pragma unroll
        for (int n = 0; n < 9; ++n) {
            const int dy = n / 3 - 1, dx = n % 3 - 1;
            mg[n] = vld[n] ? mimgg[pixg + dy * WW + dx] : 0.0f;
        }
        const float gx = (mg[2] - mg[0]) + 2.0f * (mg[5] - mg[3]) + (mg[8] - mg[6]);
        const float gy = (mg[6] - mg[0]) + 2.0f * (mg[7] - mg[1]) + (mg[8] - mg[2]);
        const float sg2 = gx * gx + gy * gy + 1e-8f;  // spatial_grad^2 (sqrt folded)
        const float al = abgg[b * 3 + 0], be = abgg[b * 3 + 1], ga = abgg[b * 3 + 2];
        out[pixg] = sqrtf(al * sg2 + be * spec * spec + ga * mix * mix + 1e-8f);
    }
}

// ============ fallback: round-8 fused kernel (used if ws too small) ==========
__global__ void __launch_bounds__(256, 2) holo_kernel(
        const float* __restrict__ x, const float* __restrict__ meta,
        const float* __restrict__ w1, const float* __restrict__ b1,
        const float* __restrict__ w2, const float* __restrict__ b2,
        float* __restrict__ out, Kers kers) {
    __shared__ __align__(16) ushort xs[NCOL * CSX];
    __shared__ __align__(16) ushort vol[NCOL * CSV];
    __shared__ float mimg[NCOL];
    __shared__ float hbuf[24];
    __shared__ float abg[3];

    const int tid = threadIdx.x;
    const int wg  = blockIdx.x;
    const int swz = (wg & 7) * 256 + (wg >> 3);
    const int b   = swz >> 8;
    const int rem = swz & 255;
    const int h0  = (rem >> 4) * TH;
    const int w0  = (rem & 15) * TW;

    if (tid < 24) {
        float s = b1[tid];
        #pragma unroll
        for (int i = 0; i < 12; ++i) s = fmaf(meta[b * 12 + i], w1[tid * 12 + i], s);
        hbuf[tid] = fmaxf(s, 0.0f);
    }
    const float* xb = x + (size_t)b * (CC * HWs);
    for (int idx = tid; idx < NCOL * 46; idx += 256) {
        const int q  = idx % NCOL;
        const int s4 = idx / NCOL;
        uint lo = 0, hi = 0;
        if (s4 >= 6 && s4 < 38) {
            const int c  = 4 * s4 - XPAD;
            const int hh = h0 - 1 + q / NCX, ww = w0 - 1 + q % NCX;
            if ((unsigned)hh < HH && (unsigned)ww < WW) {
                const float* gp = xb + (size_t)c * HWs + hh * WW + ww;
                lo = (uint)f2bf(gp[0])       | ((uint)f2bf(gp[HWs])     << 16);
                hi = (uint)f2bf(gp[2 * HWs]) | ((uint)f2bf(gp[3 * HWs]) << 16);
            }
        }
        *(uint2*)(xs + q * CSX + 4 * s4) = make_uint2(lo, hi);
    }
    __syncthreads();
    if (tid < 3) {
        float s = b2[tid];
        #pragma unroll
        for (int j = 0; j < 24; ++j) s = fmaf(hbuf[j], w2[tid * 24 + j], s);
        abg[tid] = 1.0f / (1.0f + expf(-s));
    }
    for (int it = tid; it < NCOL * 4; it += 256) {
        const int q = it % NCOL, k = it / NCOL;
        const uint4* wp = (const uint4*)(xs + q * CSX + 8 + 32 * k);
        float f2[64];
        #pragma unroll
        for (int t = 0; t < 8; ++t) {
            uint4 u = wp[t];
            f2[8*t+0]=bflo(u.x); f2[8*t+1]=bfhi(u.x); f2[8*t+2]=bflo(u.y); f2[8*t+3]=bfhi(u.y);
            f2[8*t+4]=bflo(u.z); f2[8*t+5]=bfhi(u.z); f2[8*t+6]=bflo(u.w); f2[8*t+7]=bfhi(u.w);
        }
        uint ov[16];
        #pragma unroll
        for (int m = 0; m < 32; ++m) {
            float s = 0.0f;
            #pragma unroll
            for (int j = 0; j < K19; ++j) s = fmaf(kers.k19[j], f2[m + 7 + j], s);
            const ushort hv = f2bf(fabsf(s));
            if ((m & 1) == 0) ov[m >> 1] = hv; else ov[m >> 1] |= (uint)hv << 16;
        }
        uint4* vp = (uint4*)(vol + q * CSV + VSUB * k);
        vp[0] = make_uint4(ov[0],  ov[1],  ov[2],  ov[3]);
        vp[1] = make_uint4(ov[4],  ov[5],  ov[6],  ov[7]);
        vp[2] = make_uint4(ov[8],  ov[9],  ov[10], ov[11]);
        vp[3] = make_uint4(ov[12], ov[13], ov[14], ov[15]);
    }
    if (tid >= 156) {
        const int col = tid - 156;
        const uint4* cp = (const uint4*)(xs + col * CSX + XPAD);
        float s = 0.0f;
        #pragma unroll
        for (int t = 0; t < 16; ++t) {
            uint4 u = cp[t];
            s += bflo(u.x) + bfhi(u.x) + bflo(u.y) + bfhi(u.y)
               + bflo(u.z) + bfhi(u.z) + bflo(u.w) + bfhi(u.w);
        }
        mimg[col] = s * (1.0f / CC);
    }
    __syncthreads();

    const int p = tid >> 2, sub = tid & 3;
    const int py = p >> 3, px = p & 7;
    const int q  = (py + 1) * NCX + (px + 1);
    float g1 = 0.0f, g3 = 0.0f;
    {
        float f[80];
        const uint4* ap = (const uint4*)(xs + q * CSX + 32 * sub);
        #pragma unroll
        for (int t = 0; t < 10; ++t) {
            uint4 u = ap[t];
            f[8*t+0]=bflo(u.x); f[8*t+1]=bfhi(u.x); f[8*t+2]=bflo(u.y); f[8*t+3]=bfhi(u.y);
            f[8*t+4]=bflo(u.z); f[8*t+5]=bfhi(u.z); f[8*t+6]=bflo(u.w); f[8*t+7]=bfhi(u.w);
        }
        #pragma unroll
        for (int m = 0; m < 32; ++m) {
            float s43 = 0.0f;
            #pragma unroll
            for (int j = 0; j < K43; ++j) s43 = fmaf(kers.k43[j], f[m + 3 + j], s43);
            float s7 = 0.0f;
            #pragma unroll
            for (int j = 0; j < K7; ++j) s7 = fmaf(kers.k7[j], f[m + 21 + j], s7);
            g3 += fabsf(s43);
            g1 += fabsf(s7);
        }
    }
    float g2 = 0.0f, macc = 0.0f;
    const int nq[9] = { q-11, q-10, q-9, q-1, q, q+1, q+9, q+10, q+11 };
    #pragma unroll
    for (int ss = 0; ss < 4; ++ss) {
        uint4 u[9];
        #pragma unroll
        for (int n = 0; n < 9; ++n)
            u[n] = *(const uint4*)(vol + nq[n] * CSV + sub * VSUB + 8 * ss);
        #pragma unroll
        for (int t = 0; t < 8; ++t) {
            float v[9];
            #pragma unroll
            for (int n = 0; n < 9; ++n) {
                const uint wsel = (t & 4) ? ((t & 2) ? u[n].w : u[n].z)
                                          : ((t & 2) ? u[n].y : u[n].x);
                v[n] = (t & 1) ? bfhi(wsel) : bflo(wsel);
            }
            g2 += v[4];
            const float mx = (v[2] - v[0]) + 2.0f * (v[5] - v[3]) + (v[8] - v[6]);
            const float my = (v[6] - v[0]) + 2.0f * (v[7] - v[1]) + (v[8] - v[2]);
            macc += sqrtf(mx * mx + my * my + 1e-8f);
        }
    }
    g1   += __shfl_xor(g1, 1);   g1   += __shfl_xor(g1, 2);
    g2   += __shfl_xor(g2, 1);   g2   += __shfl_xor(g2, 2);
    g3   += __shfl_xor(g3, 1);   g3   += __shfl_xor(g3, 2);
    macc += __shfl_xor(macc, 1); macc += __shfl_xor(macc, 2);
    if (sub == 0) {
        const float spec = fmaxf(fmaxf(g1, g2), g3) * (1.0f / CC);
        const float mix  = macc * (1.0f / CC);
        const float m_mm = mimg[q-11], m_m0 = mimg[q-10], m_mp = mimg[q-9];
        const float m_0m = mimg[q-1],                      m_0p = mimg[q+1];
        const float m_pm = mimg[q+9],  m_p0 = mimg[q+10],  m_pp = mimg[q+11];
        const float gx = (m_mp - m_mm) + 2.0f * (m_0p - m_0m) + (m_pp - m_pm);
        const float gy = (m_pm - m_mm) + 2.0f * (m_p0 - m_m0) + (m_pp - m_mp);
        const float sg2 = gx * gx + gy * gy + 1e-8f;
        const float al = abg[0], be = abg[1], ga = abg[2];
        const float o = sqrtf(al * sg2 + be * spec * spec + ga * mix * mix + 1e-8f);
        out[((size_t)b * HH + (h0 + py)) * WW + (w0 + px)] = o;
    }
}

// ---------------- host side --------------------------------------------------
static void make_ker(float sigma, int k, float* outk) {
    int half = k / 2;
    float asum = 0.0f;
    for (int i = 0; i < k; ++i) {
        float xx = (float)(i - half);
        float v = -xx / (sigma * sigma * sigma) * expf(-xx * xx / (2.0f * sigma * sigma));
        outk[i] = v;
        asum += fabsf(v);
    }
    for (int i = 0; i < k; ++i) outk[i] /= asum;
}

extern "C" void kernel_launch(void* const* d_in, const int* in_sizes, int n_in,
                              void* d_out, int out_size, void* d_ws, size_t ws_size,
                              hipStream_t stream) {
    const float* x    = (const float*)d_in[0];
    const float* meta = (const float*)d_in[1];
    const float* w1   = (const float*)d_in[2];
    const float* b1   = (const float*)d_in[3];
    const float* w2   = (const float*)d_in[4];
    const float* b2   = (const float*)d_in[5];
    float* outp = (float*)d_out;

    Kers kers;
    make_ker(1.0f, K7,  kers.k7);
    make_ker(3.0f, K19, kers.k19);
    make_ker(7.0f, K43, kers.k43);

    const size_t VOLB  = (size_t)BB * HH * WW * CC * sizeof(ushort); // 33,554,432
    const size_t MIMGB = (size_t)BB * HH * WW * sizeof(float);       //    524,288
    const size_t ABGB  = 24 * sizeof(float);

    if (ws_size >= VOLB + MIMGB + ABGB) {
        ushort* volg  = (ushort*)d_ws;
        float*  mimgg = (float*)((char*)d_ws + VOLB);
        float*  abgg  = (float*)((char*)d_ws + VOLB + MIMGB);
        vol_kernel<<<BB * 16 * 16, 256, 0, stream>>>(x, meta, w1, b1, w2, b2,
                                                     volg, mimgg, abgg, kers);
        grad_kernel<<<BB * 16 * 16, 256, 0, stream>>>(x, volg, mimgg, abgg,
                                                      outp, kers);
    } else {
        holo_kernel<<<BB * 16 * 16, 256, 0, stream>>>(x, meta, w1, b1, w2, b2,
                                                      outp, kers);
    }
}